// Round 9
// baseline (216.408 us; speedup 1.0000x reference)
//
#include <hip/hip_runtime.h>

typedef __attribute__((ext_vector_type(8))) short bt8;   // 8 bf16 (4 VGPR)
typedef __attribute__((ext_vector_type(4))) float f32x4; // 4 f32

__device__ __forceinline__ float bf2f(ushort u) {
    union { unsigned int i; float f; } v; v.i = ((unsigned int)u) << 16; return v.f;
}
__device__ __forceinline__ ushort f2bf(float f) {
    union { float f; unsigned int i; } v; v.f = f;
    unsigned int r = v.i + 0x7fffu + ((v.i >> 16) & 1u);
    return (ushort)(r >> 16);
}

#define GLOAD_LDS16(gp, lp) __builtin_amdgcn_global_load_lds( \
    (const __attribute__((address_space(1))) unsigned int*)(gp), \
    (__attribute__((address_space(3))) unsigned int*)(lp), 16, 0, 0)

// ---------------- fused f32 -> bf16 convert for doc + rel
__global__ __launch_bounds__(256) void cvt_two(
    const float* __restrict__ a, const float* __restrict__ b,
    ushort* __restrict__ oa, ushort* __restrict__ ob, int n1, int n2) {
    int i = blockIdx.x * 256 + threadIdx.x;
    if (i < n1) oa[i] = f2bf(a[i]);
    else if (i < n1 + n2) ob[i - n1] = f2bf(b[i - n1]);
}

// ---------------- batched weight transpose+convert: 7x W[768,768] f32 -> WT bf16 (out,in)
__global__ void transpose_all(const float* __restrict__ p0, const float* __restrict__ p1,
                              const float* __restrict__ p2, const float* __restrict__ p3,
                              const float* __restrict__ p4, const float* __restrict__ p5,
                              const float* __restrict__ p6, ushort* __restrict__ out) {
    __shared__ float t[32][33];
    const float* W;
    switch (blockIdx.z) {
        case 0: W = p0; break; case 1: W = p1; break; case 2: W = p2; break;
        case 3: W = p3; break; case 4: W = p4; break; case 5: W = p5; break;
        default: W = p6; break;
    }
    ushort* WT = out + (size_t)blockIdx.z * 768 * 768;
    int bx = blockIdx.x * 32, by = blockIdx.y * 32;
    int x = threadIdx.x, y0 = threadIdx.y;
    for (int y = y0; y < 32; y += 8)
        t[y][x] = W[(size_t)(by + y) * 768 + bx + x];
    __syncthreads();
    for (int y = y0; y < 32; y += 8)
        WT[(size_t)(bx + y) * 768 + by + x] = f2bf(t[x][y]);
}

// ---------------- m97-style MFMA GEMM 128x128: global_load_lds w16, linear LDS
template<bool BF16O>
__global__ __launch_bounds__(256) void gemm_gl(
    const ushort* __restrict__ A, const ushort* __restrict__ BT,
    void* __restrict__ Cv, int M, int N, int K)
{
    __shared__ ushort As[128 * 32];
    __shared__ ushort Bs[128 * 32];
    const int tid = threadIdx.x;
    const int wave = tid >> 6, lane = tid & 63;
    const int row0 = blockIdx.x * 128, col0 = blockIdx.y * 128;
    const int wm = (wave >> 1) * 64, wn = (wave & 1) * 64;
    const int lr = lane & 15, lk = (lane >> 4) * 8;
    const int srow = wave * 16 + (lane >> 2);
    const int scol = (lane & 3) * 8;

    f32x4 acc[4][4];
    #pragma unroll
    for (int mi = 0; mi < 4; ++mi)
        #pragma unroll
        for (int ni = 0; ni < 4; ++ni)
            acc[mi][ni] = (f32x4){0.f, 0.f, 0.f, 0.f};

    int ar0 = row0 + srow;       if (ar0 >= M) ar0 = M - 1;
    int ar1 = row0 + 64 + srow;  if (ar1 >= M) ar1 = M - 1;
    const int bc0 = col0 + srow, bc1 = col0 + 64 + srow;

    for (int kt = 0; kt < K; kt += 32) {
        __syncthreads();
        GLOAD_LDS16(A + (size_t)ar0 * K + kt + scol, As + wave * 512);
        GLOAD_LDS16(A + (size_t)ar1 * K + kt + scol, As + 2048 + wave * 512);
        GLOAD_LDS16(BT + (size_t)bc0 * K + kt + scol, Bs + wave * 512);
        GLOAD_LDS16(BT + (size_t)bc1 * K + kt + scol, Bs + 2048 + wave * 512);
        __syncthreads();
        bt8 af[4], bf[4];
        #pragma unroll
        for (int mi = 0; mi < 4; ++mi)
            af[mi] = *(const bt8*)&As[(wm + mi * 16 + lr) * 32 + lk];
        #pragma unroll
        for (int ni = 0; ni < 4; ++ni)
            bf[ni] = *(const bt8*)&Bs[(wn + ni * 16 + lr) * 32 + lk];
        #pragma unroll
        for (int mi = 0; mi < 4; ++mi)
            #pragma unroll
            for (int ni = 0; ni < 4; ++ni)
                acc[mi][ni] = __builtin_amdgcn_mfma_f32_16x16x32_bf16(
                    af[mi], bf[ni], acc[mi][ni], 0, 0, 0);
    }

    #pragma unroll
    for (int mi = 0; mi < 4; ++mi) {
        int orow0 = row0 + wm + mi * 16 + (lane >> 4) * 4;
        #pragma unroll
        for (int ni = 0; ni < 4; ++ni) {
            int ocol = col0 + wn + ni * 16 + lr;
            if (ocol >= N) continue;
            #pragma unroll
            for (int r2 = 0; r2 < 4; ++r2) {
                int orow = orow0 + r2;
                if (orow < M) {
                    if (BF16O)
                        ((ushort*)Cv)[(size_t)orow * N + ocol] = f2bf(acc[mi][ni][r2]);
                    else
                        ((float*)Cv)[(size_t)orow * N + ocol] = acc[mi][ni][r2];
                }
            }
        }
    }
}

// ---------------- 64x64 MFMA GEMM for small/narrow shapes (better grid fill)
template<bool BF16O>
__global__ __launch_bounds__(256) void gemm64(
    const ushort* __restrict__ A, const ushort* __restrict__ BT,
    void* __restrict__ Cv, int M, int N, int K)
{
    __shared__ ushort As[64 * 32];
    __shared__ ushort Bs[64 * 32];
    const int tid = threadIdx.x;
    const int wave = tid >> 6, lane = tid & 63;
    const int row0 = blockIdx.x * 64, col0 = blockIdx.y * 64;
    const int wm = (wave >> 1) * 32, wn = (wave & 1) * 32;
    const int lr = lane & 15, lk = (lane >> 4) * 8;
    const int srow = tid >> 2;          // 0..63
    const int scol = (tid & 3) * 8;

    f32x4 acc[2][2];
    #pragma unroll
    for (int mi = 0; mi < 2; ++mi)
        #pragma unroll
        for (int ni = 0; ni < 2; ++ni)
            acc[mi][ni] = (f32x4){0.f, 0.f, 0.f, 0.f};

    int ar = row0 + srow; if (ar >= M) ar = M - 1;
    const int bc = col0 + srow;

    for (int kt = 0; kt < K; kt += 32) {
        __syncthreads();
        GLOAD_LDS16(A + (size_t)ar * K + kt + scol, As + wave * 512);
        GLOAD_LDS16(BT + (size_t)bc * K + kt + scol, Bs + wave * 512);
        __syncthreads();
        bt8 af[2], bf[2];
        #pragma unroll
        for (int mi = 0; mi < 2; ++mi)
            af[mi] = *(const bt8*)&As[(wm + mi * 16 + lr) * 32 + lk];
        #pragma unroll
        for (int ni = 0; ni < 2; ++ni)
            bf[ni] = *(const bt8*)&Bs[(wn + ni * 16 + lr) * 32 + lk];
        #pragma unroll
        for (int mi = 0; mi < 2; ++mi)
            #pragma unroll
            for (int ni = 0; ni < 2; ++ni)
                acc[mi][ni] = __builtin_amdgcn_mfma_f32_16x16x32_bf16(
                    af[mi], bf[ni], acc[mi][ni], 0, 0, 0);
    }

    #pragma unroll
    for (int mi = 0; mi < 2; ++mi) {
        int orow0 = row0 + wm + mi * 16 + (lane >> 4) * 4;
        #pragma unroll
        for (int ni = 0; ni < 2; ++ni) {
            int ocol = col0 + wn + ni * 16 + lr;
            if (ocol >= N) continue;
            #pragma unroll
            for (int r2 = 0; r2 < 4; ++r2) {
                int orow = orow0 + r2;
                if (orow < M) {
                    if (BF16O)
                        ((ushort*)Cv)[(size_t)orow * N + ocol] = f2bf(acc[mi][ni][r2]);
                    else
                        ((float*)Cv)[(size_t)orow * N + ocol] = acc[mi][ni][r2];
                }
            }
        }
    }
}

// ---------------- per-(b) column sums of rel K/V from fused rkv (bf16, stride 1536)
__global__ void relsum(const ushort* __restrict__ rkv,
                       float* __restrict__ rks, float* __restrict__ rvs) {
    int b = blockIdx.x;
    int c = blockIdx.y * 256 + threadIdx.x;
    float s1 = 0.f, s2 = 0.f;
    for (int r = 0; r < 97; ++r) {
        const ushort* row = rkv + (size_t)(b * 97 + r) * 1536;
        s1 += bf2f(row[c]);
        s2 += bf2f(row[768 + c]);
    }
    rks[b * 768 + c] = s1;
    rvs[b * 768 + c] = s2;
}

// ---------------- fused_k/fused_v (bf16)
__global__ __launch_bounds__(256) void fusekv(
    const ushort* __restrict__ qkv, const float* __restrict__ rks,
    const float* __restrict__ rvs, ushort* __restrict__ kf, ushort* __restrict__ vf)
{
    int row = blockIdx.x;
    int c = blockIdx.y * 256 + threadIdx.x;
    int b = row >> 10;
    size_t qi = (size_t)row * 2304;
    size_t oi = (size_t)row * 768 + c;
    kf[oi] = f2bf(bf2f(qkv[qi + 768 + c]) + rks[b * 768 + c]);
    vf[oi] = f2bf(bf2f(qkv[qi + 1536 + c]) + rvs[b * 768 + c]);
}

// ---------------- MFMA flash attention partial (split-K), exp2 softmax, defer-max
// Block: 256 thr = 4 waves, each wave owns 32 q-rows (block = 128 q-rows).
#define SC2 0.18033688011112042f   // 0.125 * log2(e)
#define THR2 10.0f

__global__ __launch_bounds__(256) void attn_mfma(
    const ushort* __restrict__ Qp, int qstride, size_t qbstride, int qmax,
    const ushort* __restrict__ Kp, const ushort* __restrict__ Vp,
    int kvstride, size_t kvbstride,
    const int* __restrict__ mask,
    float* __restrict__ Mo, float* __restrict__ Lo, ushort* __restrict__ Oo,
    int nspl, int ntiles, int qrows)
{
    __shared__ ushort Ks[64 * 64];      // [key][k], hw ^= (key&7)<<3
    __shared__ ushort Vt[64 * 64];      // [d][key], hw ^= (d&7)<<3
    __shared__ ushort Ps[4][32 * 64];   // per-wave [qrow(32)][key], hw ^= (row&7)<<3
    __shared__ float  madd[64];

    const int tid = threadIdx.x;
    const int wv = tid >> 6, lane = tid & 63;
    const int lr = lane & 15, lk = (lane >> 4) * 8, rg = lane >> 4;
    const int bh = blockIdx.x, b = bh / 12, h = bh % 12;
    const int qb = blockIdx.y, spl = blockIdx.z;
    const int q0 = qb * 128 + wv * 32;

    const size_t kvbase = (size_t)b * kvbstride + h * 64;
    const size_t qbase  = (size_t)b * qbstride + h * 64;

    // Q fragments for 2 row-halves (bf16 direct)
    bt8 qf[2][2];
    #pragma unroll
    for (int qh = 0; qh < 2; ++qh) {
        const int qi = q0 + qh * 16 + lr;
        if (qi < qmax) {
            const ushort* qp = Qp + qbase + (size_t)qi * qstride + lk;
            qf[qh][0] = *(const bt8*)qp;
            qf[qh][1] = *(const bt8*)(qp + 32);
        } else {
            #pragma unroll
            for (int j = 0; j < 8; ++j) { qf[qh][0][j] = 0; qf[qh][1][j] = 0; }
        }
    }

    f32x4 acc[2][4];
    #pragma unroll
    for (int qh = 0; qh < 2; ++qh)
        #pragma unroll
        for (int dg = 0; dg < 4; ++dg) acc[qh][dg] = (f32x4){0.f, 0.f, 0.f, 0.f};
    float m_r[8], l_r[8];
    #pragma unroll
    for (int r = 0; r < 8; ++r) { m_r[r] = -3.0e38f; l_r[r] = 0.f; }

    const int key = tid >> 2, c0 = (tid & 3) * 16;  // K staging
    const int vd = tid & 63, vw = tid >> 6;         // V staging (column gather)
    const int swk = (key & 7) << 3;
    const int swv = (vd & 7) << 3;
    const int swl = (lr & 7) << 3;

    for (int t = 0; t < ntiles; ++t) {
        const int k0 = (spl * ntiles + t) * 64;
        __syncthreads();
        {
            const ushort* src = Kp + kvbase + (size_t)(k0 + key) * kvstride + c0;
            int4 a = *(const int4*)src;
            int4 bq = *(const int4*)(src + 8);
            *(int4*)&Ks[key * 64 + (c0 ^ swk)] = a;
            *(int4*)&Ks[key * 64 + ((c0 + 8) ^ swk)] = bq;
        }
        {
            const ushort* vsrc = Vp + kvbase + (size_t)(k0 + vw * 16) * kvstride + vd;
            ushort tv[16];
            #pragma unroll
            for (int j = 0; j < 16; ++j) tv[j] = vsrc[(size_t)j * kvstride];
            const int cc = vw * 16;
            *(int4*)&Vt[vd * 64 + (cc ^ swv)] = *(int4*)tv;
            *(int4*)&Vt[vd * 64 + ((cc + 8) ^ swv)] = *(int4*)(tv + 8);
        }
        if (tid < 64)
            madd[tid] = (mask[b * 1024 + k0 + tid] == 0) ? -1e30f : 0.f;
        __syncthreads();

        #pragma unroll
        for (int qh = 0; qh < 2; ++qh) {
            // S = Q K^T (swizzled Ks reads)
            f32x4 sf[4];
            #pragma unroll
            for (int kg = 0; kg < 4; ++kg) {
                f32x4 s4 = (f32x4){0.f, 0.f, 0.f, 0.f};
                #pragma unroll
                for (int kk = 0; kk < 2; ++kk) {
                    bt8 kf2 = *(const bt8*)&Ks[(kg * 16 + lr) * 64 + ((kk * 32 + lk) ^ swl)];
                    s4 = __builtin_amdgcn_mfma_f32_16x16x32_bf16(qf[qh][kk], kf2, s4, 0, 0, 0);
                }
                sf[kg] = s4;
            }

            // online softmax in exp2 domain, per reg r
            #pragma unroll
            for (int r = 0; r < 4; ++r) {
                const int ri = qh * 4 + r;
                float sv0 = sf[0][r] * SC2 + madd[lr];
                float sv1 = sf[1][r] * SC2 + madd[16 + lr];
                float sv2 = sf[2][r] * SC2 + madd[32 + lr];
                float sv3 = sf[3][r] * SC2 + madd[48 + lr];
                float mx = fmaxf(fmaxf(sv0, sv1), fmaxf(sv2, sv3));
                mx = fmaxf(mx, __shfl_xor(mx, 1));
                mx = fmaxf(mx, __shfl_xor(mx, 2));
                mx = fmaxf(mx, __shfl_xor(mx, 4));
                mx = fmaxf(mx, __shfl_xor(mx, 8));
                float m_old = m_r[ri];
                if (mx > m_old + THR2) {   // defer-max: rescale only on real growth
                    float corr = exp2f(m_old - mx);
                    m_r[ri] = mx;
                    l_r[ri] *= corr;
                    #pragma unroll
                    for (int dg = 0; dg < 4; ++dg) acc[qh][dg][r] *= corr;
                }
                const float mn = m_r[ri];
                float p0 = exp2f(sv0 - mn), p1 = exp2f(sv1 - mn);
                float p2 = exp2f(sv2 - mn), p3 = exp2f(sv3 - mn);
                float ps = (p0 + p1) + (p2 + p3);
                ps += __shfl_xor(ps, 1);
                ps += __shfl_xor(ps, 2);
                ps += __shfl_xor(ps, 4);
                ps += __shfl_xor(ps, 8);
                l_r[ri] += ps;
                const int rowq = qh * 16 + rg * 4 + r;
                const int swp = (rowq & 7) << 3;
                Ps[wv][rowq * 64 + ((0 * 16 + lr) ^ swp)] = f2bf(p0);
                Ps[wv][rowq * 64 + ((1 * 16 + lr) ^ swp)] = f2bf(p1);
                Ps[wv][rowq * 64 + ((2 * 16 + lr) ^ swp)] = f2bf(p2);
                Ps[wv][rowq * 64 + ((3 * 16 + lr) ^ swp)] = f2bf(p3);
            }
        }

        // PV for both halves (swizzled Ps / Vt reads)
        #pragma unroll
        for (int qh = 0; qh < 2; ++qh) {
            #pragma unroll
            for (int kk = 0; kk < 2; ++kk) {
                bt8 pa = *(const bt8*)&Ps[wv][(qh * 16 + lr) * 64 + ((kk * 32 + lk) ^ swl)];
                #pragma unroll
                for (int dg = 0; dg < 4; ++dg) {
                    bt8 vf2 = *(const bt8*)&Vt[(dg * 16 + lr) * 64 + ((kk * 32 + lk) ^ swl)];
                    acc[qh][dg] = __builtin_amdgcn_mfma_f32_16x16x32_bf16(pa, vf2, acc[qh][dg], 0, 0, 0);
                }
            }
        }
    }

    // write partials
    if (lr == 0) {
        #pragma unroll
        for (int qh = 0; qh < 2; ++qh)
            #pragma unroll
            for (int r = 0; r < 4; ++r) {
                int qi = q0 + qh * 16 + rg * 4 + r;
                int prow = (bh * nspl + spl) * qrows + qi;
                Mo[prow] = m_r[qh * 4 + r];
                Lo[prow] = l_r[qh * 4 + r];
            }
    }
    #pragma unroll
    for (int qh = 0; qh < 2; ++qh)
        #pragma unroll
        for (int r = 0; r < 4; ++r) {
            int qi = q0 + qh * 16 + rg * 4 + r;
            size_t orow = ((size_t)(bh * nspl + spl) * qrows + qi) * 64;
            #pragma unroll
            for (int dg = 0; dg < 4; ++dg)
                Oo[orow + dg * 16 + lr] = f2bf(acc[qh][dg][r]);
        }
}

// ---------------- merge split partials (exp2 domain) -> psi (bf16)
__global__ __launch_bounds__(64) void attn_merge(
    const float* __restrict__ Mo, const float* __restrict__ Lo, const ushort* __restrict__ Oo,
    const ushort* __restrict__ resid, size_t rbstride, int rstride,
    ushort* __restrict__ psi,
    int nspl, int qrows, int qmax, int out_rows)
{
    const int tid = threadIdx.x, bh = blockIdx.x, qb = blockIdx.y;
    const int b = bh / 12, h = bh % 12;
    const int qi = qb * 64 + tid;
    if (qi >= qmax) return;
    const int pb = bh * nspl;

    float M = -3.0e38f;
    for (int s = 0; s < nspl; ++s)
        M = fmaxf(M, Mo[(pb + s) * qrows + qi]);
    float L = 0.f, O[64];
    #pragma unroll
    for (int d = 0; d < 64; ++d) O[d] = 0.f;
    for (int s = 0; s < nspl; ++s) {
        int pr = (pb + s) * qrows + qi;
        float f = exp2f(Mo[pr] - M);
        L += Lo[pr] * f;
        const uint* op = (const uint*)(Oo + (size_t)pr * 64);
        #pragma unroll
        for (int d2 = 0; d2 < 32; ++d2) {
            uint u = op[d2];
            O[2*d2]   += f * bf2f((ushort)(u & 0xffffu));
            O[2*d2+1] += f * bf2f((ushort)(u >> 16));
        }
    }
    const float rl = 1.f / L;
    const size_t ob = ((size_t)b * out_rows + qi) * 768 + h * 64;
    if (resid) {
        const ushort* rp = resid + (size_t)b * rbstride + (size_t)qi * rstride + h * 64;
        #pragma unroll
        for (int d = 0; d < 64; ++d)
            psi[ob + d] = f2bf(O[d] * rl + bf2f(rp[d]));
    } else {
        #pragma unroll
        for (int d = 0; d < 64; ++d)
            psi[ob + d] = f2bf(O[d] * rl);
    }
}

// ---------------- LayerNorm( gin + residual ) * g + b  -> f32 out
__global__ __launch_bounds__(256) void ln_ker(
    const float* __restrict__ gin, const float* __restrict__ resid,
    const float* __restrict__ g, const float* __restrict__ bta,
    float* __restrict__ out)
{
    const int row = blockIdx.x, tid = threadIdx.x;
    const size_t rb = (size_t)row * 768;
    float x[3], s = 0.f, s2 = 0.f;
    #pragma unroll
    for (int k2 = 0; k2 < 3; ++k2) {
        int c = k2 * 256 + tid;
        float v = gin[rb + c] + resid[rb + c];
        x[k2] = v; s += v; s2 += v * v;
    }
    #pragma unroll
    for (int off = 32; off > 0; off >>= 1) {
        s  += __shfl_down(s, off);
        s2 += __shfl_down(s2, off);
    }
    __shared__ float red[10];
    const int wv = tid >> 6;
    if ((tid & 63) == 0) { red[wv] = s; red[4 + wv] = s2; }
    __syncthreads();
    if (tid == 0) {
        float ts = red[0] + red[1] + red[2] + red[3];
        float t2 = red[4] + red[5] + red[6] + red[7];
        float mean = ts * (1.f / 768.f);
        float var = t2 * (1.f / 768.f) - mean * mean;
        red[8] = mean;
        red[9] = rsqrtf(fmaxf(var, 0.f) + 1e-6f);
    }
    __syncthreads();
    const float mean = red[8], rstd = red[9];
    #pragma unroll
    for (int k2 = 0; k2 < 3; ++k2) {
        int c = k2 * 256 + tid;
        out[rb + c] = (x[k2] - mean) * rstd * g[c] + bta[c];
    }
}

extern "C" void kernel_launch(void* const* d_in, const int* in_sizes, int n_in,
                              void* d_out, int out_size, void* d_ws, size_t ws_size,
                              hipStream_t stream) {
    const float* doc  = (const float*)d_in[0];
    const float* rel  = (const float*)d_in[1];
    const int*   mask = (const int*)d_in[2];
    const float* ln_dg = (const float*)d_in[10];
    const float* ln_db = (const float*)d_in[11];
    const float* ln_rg = (const float*)d_in[12];
    const float* ln_rb = (const float*)d_in[13];

    char* ws = (char*)d_ws;
    size_t off = 0;
    ushort* wtall = (ushort*)(ws + off); off += (size_t)7 * 768 * 768 * 2;
    ushort* wtqkv = wtall;
    ushort* wt34  = wtall + (size_t)3 * 768 * 768;
    ushort* wt5   = wtall + (size_t)5 * 768 * 768;
    ushort* wt6   = wtall + (size_t)6 * 768 * 768;
    ushort* doc_bf = (ushort*)(ws + off); off += (size_t)4096 * 768 * 2;
    ushort* rel_bf = (ushort*)(ws + off); off += (size_t)388 * 768 * 2;
    ushort* qkv_bf = (ushort*)(ws + off); off += (size_t)4096 * 2304 * 2;
    ushort* rkv_bf = (ushort*)(ws + off); off += (size_t)388 * 1536 * 2;
    float*  rks = (float*)(ws + off); off += (size_t)4 * 768 * 4;
    float*  rvs = (float*)(ws + off); off += (size_t)4 * 768 * 4;
    ushort* kf_bf = (ushort*)(ws + off); off += (size_t)4096 * 768 * 2;
    ushort* vf_bf = (ushort*)(ws + off); off += (size_t)4096 * 768 * 2;
    ushort* psi_i = (ushort*)(ws + off); off += (size_t)4096 * 768 * 2;
    ushort* psi_r = (ushort*)(ws + off); off += (size_t)388 * 768 * 2;
    float*  Mo = (float*)(ws + off);  off += (size_t)48 * 2 * 1024 * 4;
    float*  Lo = (float*)(ws + off);  off += (size_t)48 * 2 * 1024 * 4;
    ushort* Oo = (ushort*)(ws + off); off += (size_t)48 * 2 * 1024 * 64 * 2;
    float*  gdoc = (float*)(ws + off); off += (size_t)4096 * 768 * 4;
    float*  grel = (float*)(ws + off); off += (size_t)388 * 768 * 4;

    float* out_doc = (float*)d_out;
    float* out_rel = out_doc + (size_t)4096 * 768;

    // input converts + batched weight transpose
    const int n1 = 4096 * 768, n2 = 388 * 768;
    cvt_two<<<dim3((n1 + n2 + 255) / 256), 256, 0, stream>>>(doc, rel, doc_bf, rel_bf, n1, n2);
    transpose_all<<<dim3(24, 24, 7), dim3(32, 8), 0, stream>>>(
        (const float*)d_in[3], (const float*)d_in[4], (const float*)d_in[5],
        (const float*)d_in[6], (const float*)d_in[7], (const float*)d_in[8],
        (const float*)d_in[9], wtall);

    // fused projections (bf16 out)
    gemm_gl<true><<<dim3(32, 18), 256, 0, stream>>>(doc_bf, wtqkv, qkv_bf, 4096, 2304, 768);
    gemm64<true><<<dim3(7, 24),  256, 0, stream>>>(rel_bf, wt34, rkv_bf, 388, 1536, 768);

    // relation sums + fused K/V (bf16)
    relsum<<<dim3(4, 3), 256, 0, stream>>>(rkv_bf, rks, rvs);
    fusekv<<<dim3(4096, 3), 256, 0, stream>>>(qkv_bf, rks, rvs, kf_bf, vf_bf);

    // rel-doc attention on RAW k/v (qkv slices): 8 splits x 2 tiles, 1 q-block (128 rows)
    attn_mfma<<<dim3(48, 1, 8), 256, 0, stream>>>(
        rkv_bf, 1536, (size_t)97 * 1536, 97,
        qkv_bf + 768, qkv_bf + 1536, 2304, (size_t)1024 * 2304,
        mask, Mo, Lo, Oo, 8, 2, 128);
    attn_merge<<<dim3(48, 2), 64, 0, stream>>>(
        Mo, Lo, Oo, rkv_bf + 768, (size_t)97 * 1536, 1536, psi_r, 8, 128, 97, 97);

    // doc-doc attention on fused K/V: 2 splits x 8 tiles, 8 q-blocks (128 rows each)
    attn_mfma<<<dim3(48, 8, 2), 256, 0, stream>>>(
        qkv_bf, 2304, (size_t)1024 * 2304, 1024,
        kf_bf, vf_bf, 768, (size_t)1024 * 768,
        mask, Mo, Lo, Oo, 2, 8, 1024);
    attn_merge<<<dim3(48, 16), 64, 0, stream>>>(
        Mo, Lo, Oo, (const ushort*)nullptr, 0, 0, psi_i, 2, 1024, 1024, 1024);

    // output projections on 64^2 grid (3 blocks/CU)
    gemm64<false><<<dim3(64, 12), 256, 0, stream>>>(psi_i, wt5, gdoc, 4096, 768, 768);
    gemm64<false><<<dim3(7, 12),  256, 0, stream>>>(psi_r, wt6, grel, 388, 768, 768);

    // layernorm + residual -> f32 outputs
    ln_ker<<<4096, 256, 0, stream>>>(gdoc, doc, ln_dg, ln_db, out_doc);
    ln_ker<<<388,  256, 0, stream>>>(grel, rel, ln_rg, ln_rb, out_rel);
}

// Round 10
// 197.320 us; speedup vs baseline: 1.0967x; 1.0967x over previous
//
#include <hip/hip_runtime.h>

typedef __attribute__((ext_vector_type(8))) short bt8;   // 8 bf16 (4 VGPR)
typedef __attribute__((ext_vector_type(4))) float f32x4; // 4 f32

__device__ __forceinline__ float bf2f(ushort u) {
    union { unsigned int i; float f; } v; v.i = ((unsigned int)u) << 16; return v.f;
}
__device__ __forceinline__ ushort f2bf(float f) {
    union { float f; unsigned int i; } v; v.f = f;
    unsigned int r = v.i + 0x7fffu + ((v.i >> 16) & 1u);
    return (ushort)(r >> 16);
}

#define GLOAD_LDS16(gp, lp) __builtin_amdgcn_global_load_lds( \
    (const __attribute__((address_space(1))) unsigned int*)(gp), \
    (__attribute__((address_space(3))) unsigned int*)(lp), 16, 0, 0)

// ---------------- fused f32 -> bf16 convert for doc + rel
__global__ __launch_bounds__(256) void cvt_two(
    const float* __restrict__ a, const float* __restrict__ b,
    ushort* __restrict__ oa, ushort* __restrict__ ob, int n1, int n2) {
    int i = blockIdx.x * 256 + threadIdx.x;
    if (i < n1) oa[i] = f2bf(a[i]);
    else if (i < n1 + n2) ob[i - n1] = f2bf(b[i - n1]);
}

// ---------------- batched weight transpose+convert: 7x W[768,768] f32 -> WT bf16 (out,in)
__global__ void transpose_all(const float* __restrict__ p0, const float* __restrict__ p1,
                              const float* __restrict__ p2, const float* __restrict__ p3,
                              const float* __restrict__ p4, const float* __restrict__ p5,
                              const float* __restrict__ p6, ushort* __restrict__ out) {
    __shared__ float t[32][33];
    const float* W;
    switch (blockIdx.z) {
        case 0: W = p0; break; case 1: W = p1; break; case 2: W = p2; break;
        case 3: W = p3; break; case 4: W = p4; break; case 5: W = p5; break;
        default: W = p6; break;
    }
    ushort* WT = out + (size_t)blockIdx.z * 768 * 768;
    int bx = blockIdx.x * 32, by = blockIdx.y * 32;
    int x = threadIdx.x, y0 = threadIdx.y;
    for (int y = y0; y < 32; y += 8)
        t[y][x] = W[(size_t)(by + y) * 768 + bx + x];
    __syncthreads();
    for (int y = y0; y < 32; y += 8)
        WT[(size_t)(bx + y) * 768 + by + x] = f2bf(t[x][y]);
}

// ---------------- m97-style MFMA GEMM 128x128: global_load_lds w16, linear LDS
template<bool BF16O>
__global__ __launch_bounds__(256) void gemm_gl(
    const ushort* __restrict__ A, const ushort* __restrict__ BT,
    void* __restrict__ Cv, int M, int N, int K)
{
    __shared__ ushort As[128 * 32];
    __shared__ ushort Bs[128 * 32];
    const int tid = threadIdx.x;
    const int wave = tid >> 6, lane = tid & 63;
    const int row0 = blockIdx.x * 128, col0 = blockIdx.y * 128;
    const int wm = (wave >> 1) * 64, wn = (wave & 1) * 64;
    const int lr = lane & 15, lk = (lane >> 4) * 8;
    const int srow = wave * 16 + (lane >> 2);
    const int scol = (lane & 3) * 8;

    f32x4 acc[4][4];
    #pragma unroll
    for (int mi = 0; mi < 4; ++mi)
        #pragma unroll
        for (int ni = 0; ni < 4; ++ni)
            acc[mi][ni] = (f32x4){0.f, 0.f, 0.f, 0.f};

    int ar0 = row0 + srow;       if (ar0 >= M) ar0 = M - 1;
    int ar1 = row0 + 64 + srow;  if (ar1 >= M) ar1 = M - 1;
    const int bc0 = col0 + srow, bc1 = col0 + 64 + srow;

    for (int kt = 0; kt < K; kt += 32) {
        __syncthreads();
        GLOAD_LDS16(A + (size_t)ar0 * K + kt + scol, As + wave * 512);
        GLOAD_LDS16(A + (size_t)ar1 * K + kt + scol, As + 2048 + wave * 512);
        GLOAD_LDS16(BT + (size_t)bc0 * K + kt + scol, Bs + wave * 512);
        GLOAD_LDS16(BT + (size_t)bc1 * K + kt + scol, Bs + 2048 + wave * 512);
        __syncthreads();
        bt8 af[4], bf[4];
        #pragma unroll
        for (int mi = 0; mi < 4; ++mi)
            af[mi] = *(const bt8*)&As[(wm + mi * 16 + lr) * 32 + lk];
        #pragma unroll
        for (int ni = 0; ni < 4; ++ni)
            bf[ni] = *(const bt8*)&Bs[(wn + ni * 16 + lr) * 32 + lk];
        #pragma unroll
        for (int mi = 0; mi < 4; ++mi)
            #pragma unroll
            for (int ni = 0; ni < 4; ++ni)
                acc[mi][ni] = __builtin_amdgcn_mfma_f32_16x16x32_bf16(
                    af[mi], bf[ni], acc[mi][ni], 0, 0, 0);
    }

    #pragma unroll
    for (int mi = 0; mi < 4; ++mi) {
        int orow0 = row0 + wm + mi * 16 + (lane >> 4) * 4;
        #pragma unroll
        for (int ni = 0; ni < 4; ++ni) {
            int ocol = col0 + wn + ni * 16 + lr;
            if (ocol >= N) continue;
            #pragma unroll
            for (int r2 = 0; r2 < 4; ++r2) {
                int orow = orow0 + r2;
                if (orow < M) {
                    if (BF16O)
                        ((ushort*)Cv)[(size_t)orow * N + ocol] = f2bf(acc[mi][ni][r2]);
                    else
                        ((float*)Cv)[(size_t)orow * N + ocol] = acc[mi][ni][r2];
                }
            }
        }
    }
}

// ---------------- 64x64 MFMA GEMM for small/narrow shapes (better grid fill)
template<bool BF16O>
__global__ __launch_bounds__(256) void gemm64(
    const ushort* __restrict__ A, const ushort* __restrict__ BT,
    void* __restrict__ Cv, int M, int N, int K)
{
    __shared__ ushort As[64 * 32];
    __shared__ ushort Bs[64 * 32];
    const int tid = threadIdx.x;
    const int wave = tid >> 6, lane = tid & 63;
    const int row0 = blockIdx.x * 64, col0 = blockIdx.y * 64;
    const int wm = (wave >> 1) * 32, wn = (wave & 1) * 32;
    const int lr = lane & 15, lk = (lane >> 4) * 8;
    const int srow = tid >> 2;          // 0..63
    const int scol = (tid & 3) * 8;

    f32x4 acc[2][2];
    #pragma unroll
    for (int mi = 0; mi < 2; ++mi)
        #pragma unroll
        for (int ni = 0; ni < 2; ++ni)
            acc[mi][ni] = (f32x4){0.f, 0.f, 0.f, 0.f};

    int ar = row0 + srow; if (ar >= M) ar = M - 1;
    const int bc = col0 + srow;

    for (int kt = 0; kt < K; kt += 32) {
        __syncthreads();
        GLOAD_LDS16(A + (size_t)ar * K + kt + scol, As + wave * 512);
        GLOAD_LDS16(BT + (size_t)bc * K + kt + scol, Bs + wave * 512);
        __syncthreads();
        bt8 af[2], bf[2];
        #pragma unroll
        for (int mi = 0; mi < 2; ++mi)
            af[mi] = *(const bt8*)&As[(wm + mi * 16 + lr) * 32 + lk];
        #pragma unroll
        for (int ni = 0; ni < 2; ++ni)
            bf[ni] = *(const bt8*)&Bs[(wn + ni * 16 + lr) * 32 + lk];
        #pragma unroll
        for (int mi = 0; mi < 2; ++mi)
            #pragma unroll
            for (int ni = 0; ni < 2; ++ni)
                acc[mi][ni] = __builtin_amdgcn_mfma_f32_16x16x32_bf16(
                    af[mi], bf[ni], acc[mi][ni], 0, 0, 0);
    }

    #pragma unroll
    for (int mi = 0; mi < 2; ++mi) {
        int orow0 = row0 + wm + mi * 16 + (lane >> 4) * 4;
        #pragma unroll
        for (int ni = 0; ni < 2; ++ni) {
            int ocol = col0 + wn + ni * 16 + lr;
            if (ocol >= N) continue;
            #pragma unroll
            for (int r2 = 0; r2 < 4; ++r2) {
                int orow = orow0 + r2;
                if (orow < M) {
                    if (BF16O)
                        ((ushort*)Cv)[(size_t)orow * N + ocol] = f2bf(acc[mi][ni][r2]);
                    else
                        ((float*)Cv)[(size_t)orow * N + ocol] = acc[mi][ni][r2];
                }
            }
        }
    }
}

// ---------------- per-(b) column sums of rel K/V from fused rkv (bf16, stride 1536)
__global__ void relsum(const ushort* __restrict__ rkv,
                       float* __restrict__ rks, float* __restrict__ rvs) {
    int b = blockIdx.x;
    int c = blockIdx.y * 256 + threadIdx.x;
    float s1 = 0.f, s2 = 0.f;
    for (int r = 0; r < 97; ++r) {
        const ushort* row = rkv + (size_t)(b * 97 + r) * 1536;
        s1 += bf2f(row[c]);
        s2 += bf2f(row[768 + c]);
    }
    rks[b * 768 + c] = s1;
    rvs[b * 768 + c] = s2;
}

// ---------------- fused_k/fused_v (bf16)
__global__ __launch_bounds__(256) void fusekv(
    const ushort* __restrict__ qkv, const float* __restrict__ rks,
    const float* __restrict__ rvs, ushort* __restrict__ kf, ushort* __restrict__ vf)
{
    int row = blockIdx.x;
    int c = blockIdx.y * 256 + threadIdx.x;
    int b = row >> 10;
    size_t qi = (size_t)row * 2304;
    size_t oi = (size_t)row * 768 + c;
    kf[oi] = f2bf(bf2f(qkv[qi + 768 + c]) + rks[b * 768 + c]);
    vf[oi] = f2bf(bf2f(qkv[qi + 1536 + c]) + rvs[b * 768 + c]);
}

// ---------------- MFMA flash attention partial (split-K), exp2 softmax, defer-max
// Block: 256 thr = 4 waves, each wave owns 16 q-rows (block = 64 q-rows).
#define SC2 0.18033688011112042f   // 0.125 * log2(e)
#define THR2 10.0f

__global__ __launch_bounds__(256) void attn_mfma(
    const ushort* __restrict__ Qp, int qstride, size_t qbstride, int qmax,
    const ushort* __restrict__ Kp, const ushort* __restrict__ Vp,
    int kvstride, size_t kvbstride,
    const int* __restrict__ mask,
    float* __restrict__ Mo, float* __restrict__ Lo, ushort* __restrict__ Oo,
    int nspl, int ntiles, int qrows)
{
    __shared__ ushort Ks[64 * 64];      // [key][k], hw ^= (key&7)<<3
    __shared__ ushort Vt[64 * 64];      // [d][key], hw ^= (d&7)<<3
    __shared__ ushort Ps[4][16 * 64];   // per-wave [qrow][key], hw ^= (row&7)<<3
    __shared__ float  madd[64];

    const int tid = threadIdx.x;
    const int wv = tid >> 6, lane = tid & 63;
    const int lr = lane & 15, lk = (lane >> 4) * 8, rg = lane >> 4;
    const int bh = blockIdx.x, b = bh / 12, h = bh % 12;
    const int qb = blockIdx.y, spl = blockIdx.z;
    const int q0 = qb * 64 + wv * 16;

    const size_t kvbase = (size_t)b * kvbstride + h * 64;
    const size_t qbase  = (size_t)b * qbstride + h * 64;

    // Q fragments (bf16 direct)
    bt8 qf[2];
    {
        const int qi = q0 + lr;
        if (qi < qmax) {
            const ushort* qp = Qp + qbase + (size_t)qi * qstride + lk;
            qf[0] = *(const bt8*)qp;
            qf[1] = *(const bt8*)(qp + 32);
        } else {
            #pragma unroll
            for (int j = 0; j < 8; ++j) { qf[0][j] = 0; qf[1][j] = 0; }
        }
    }

    f32x4 acc[4];
    #pragma unroll
    for (int dg = 0; dg < 4; ++dg) acc[dg] = (f32x4){0.f, 0.f, 0.f, 0.f};
    float m_r[4], l_r[4];
    #pragma unroll
    for (int r = 0; r < 4; ++r) { m_r[r] = -3.0e38f; l_r[r] = 0.f; }

    const int key = tid >> 2, c0 = (tid & 3) * 16;  // K staging
    const int vd = tid & 63, vw = tid >> 6;         // V staging (column gather)
    const int swk = (key & 7) << 3;
    const int swv = (vd & 7) << 3;
    const int swl = (lr & 7) << 3;

    for (int t = 0; t < ntiles; ++t) {
        const int k0 = (spl * ntiles + t) * 64;
        __syncthreads();
        {
            const ushort* src = Kp + kvbase + (size_t)(k0 + key) * kvstride + c0;
            int4 a = *(const int4*)src;
            int4 bq = *(const int4*)(src + 8);
            *(int4*)&Ks[key * 64 + (c0 ^ swk)] = a;
            *(int4*)&Ks[key * 64 + ((c0 + 8) ^ swk)] = bq;
        }
        {
            const ushort* vsrc = Vp + kvbase + (size_t)(k0 + vw * 16) * kvstride + vd;
            ushort tv[16];
            #pragma unroll
            for (int j = 0; j < 16; ++j) tv[j] = vsrc[(size_t)j * kvstride];
            const int cc = vw * 16;
            *(int4*)&Vt[vd * 64 + (cc ^ swv)] = *(int4*)tv;
            *(int4*)&Vt[vd * 64 + ((cc + 8) ^ swv)] = *(int4*)(tv + 8);
        }
        if (tid < 64)
            madd[tid] = (mask[b * 1024 + k0 + tid] == 0) ? -1e30f : 0.f;
        __syncthreads();

        // S = Q K^T (swizzled Ks reads)
        f32x4 sf[4];
        #pragma unroll
        for (int kg = 0; kg < 4; ++kg) {
            f32x4 s4 = (f32x4){0.f, 0.f, 0.f, 0.f};
            #pragma unroll
            for (int kk = 0; kk < 2; ++kk) {
                bt8 kf2 = *(const bt8*)&Ks[(kg * 16 + lr) * 64 + ((kk * 32 + lk) ^ swl)];
                s4 = __builtin_amdgcn_mfma_f32_16x16x32_bf16(qf[kk], kf2, s4, 0, 0, 0);
            }
            sf[kg] = s4;
        }

        // online softmax in exp2 domain (per reg r = qrow), defer-max
        #pragma unroll
        for (int r = 0; r < 4; ++r) {
            float sv0 = sf[0][r] * SC2 + madd[lr];
            float sv1 = sf[1][r] * SC2 + madd[16 + lr];
            float sv2 = sf[2][r] * SC2 + madd[32 + lr];
            float sv3 = sf[3][r] * SC2 + madd[48 + lr];
            float mx = fmaxf(fmaxf(sv0, sv1), fmaxf(sv2, sv3));
            mx = fmaxf(mx, __shfl_xor(mx, 1));
            mx = fmaxf(mx, __shfl_xor(mx, 2));
            mx = fmaxf(mx, __shfl_xor(mx, 4));
            mx = fmaxf(mx, __shfl_xor(mx, 8));
            float m_old = m_r[r];
            if (mx > m_old + THR2) {
                float corr = exp2f(m_old - mx);
                m_r[r] = mx;
                l_r[r] *= corr;
                #pragma unroll
                for (int dg = 0; dg < 4; ++dg) acc[dg][r] *= corr;
            }
            const float mn = m_r[r];
            float p0 = exp2f(sv0 - mn), p1 = exp2f(sv1 - mn);
            float p2 = exp2f(sv2 - mn), p3 = exp2f(sv3 - mn);
            float ps = (p0 + p1) + (p2 + p3);
            ps += __shfl_xor(ps, 1);
            ps += __shfl_xor(ps, 2);
            ps += __shfl_xor(ps, 4);
            ps += __shfl_xor(ps, 8);
            l_r[r] += ps;
            const int rowq = rg * 4 + r;
            const int swp = (rowq & 7) << 3;
            Ps[wv][rowq * 64 + ((0 * 16 + lr) ^ swp)] = f2bf(p0);
            Ps[wv][rowq * 64 + ((1 * 16 + lr) ^ swp)] = f2bf(p1);
            Ps[wv][rowq * 64 + ((2 * 16 + lr) ^ swp)] = f2bf(p2);
            Ps[wv][rowq * 64 + ((3 * 16 + lr) ^ swp)] = f2bf(p3);
        }

        // PV (swizzled Ps / Vt reads)
        #pragma unroll
        for (int kk = 0; kk < 2; ++kk) {
            bt8 pa = *(const bt8*)&Ps[wv][lr * 64 + ((kk * 32 + lk) ^ swl)];
            #pragma unroll
            for (int dg = 0; dg < 4; ++dg) {
                bt8 vf2 = *(const bt8*)&Vt[(dg * 16 + lr) * 64 + ((kk * 32 + lk) ^ swl)];
                acc[dg] = __builtin_amdgcn_mfma_f32_16x16x32_bf16(pa, vf2, acc[dg], 0, 0, 0);
            }
        }
    }

    // write partials
    if (lr == 0) {
        #pragma unroll
        for (int r = 0; r < 4; ++r) {
            int qi = q0 + rg * 4 + r;
            int prow = (bh * nspl + spl) * qrows + qi;
            Mo[prow] = m_r[r];
            Lo[prow] = l_r[r];
        }
    }
    #pragma unroll
    for (int r = 0; r < 4; ++r) {
        int qi = q0 + rg * 4 + r;
        size_t orow = ((size_t)(bh * nspl + spl) * qrows + qi) * 64;
        #pragma unroll
        for (int dg = 0; dg < 4; ++dg)
            Oo[orow + dg * 16 + lr] = f2bf(acc[dg][r]);
    }
}

// ---------------- merge split partials (exp2 domain) -> psi (bf16)
__global__ __launch_bounds__(64) void attn_merge(
    const float* __restrict__ Mo, const float* __restrict__ Lo, const ushort* __restrict__ Oo,
    const ushort* __restrict__ resid, size_t rbstride, int rstride,
    ushort* __restrict__ psi,
    int nspl, int qrows, int qmax, int out_rows)
{
    const int tid = threadIdx.x, bh = blockIdx.x, qb = blockIdx.y;
    const int b = bh / 12, h = bh % 12;
    const int qi = qb * 64 + tid;
    if (qi >= qmax) return;
    const int pb = bh * nspl;

    float M = -3.0e38f;
    for (int s = 0; s < nspl; ++s)
        M = fmaxf(M, Mo[(pb + s) * qrows + qi]);
    float L = 0.f, O[64];
    #pragma unroll
    for (int d = 0; d < 64; ++d) O[d] = 0.f;
    for (int s = 0; s < nspl; ++s) {
        int pr = (pb + s) * qrows + qi;
        float f = exp2f(Mo[pr] - M);
        L += Lo[pr] * f;
        const uint* op = (const uint*)(Oo + (size_t)pr * 64);
        #pragma unroll
        for (int d2 = 0; d2 < 32; ++d2) {
            uint u = op[d2];
            O[2*d2]   += f * bf2f((ushort)(u & 0xffffu));
            O[2*d2+1] += f * bf2f((ushort)(u >> 16));
        }
    }
    const float rl = 1.f / L;
    const size_t ob = ((size_t)b * out_rows + qi) * 768 + h * 64;
    if (resid) {
        const ushort* rp = resid + (size_t)b * rbstride + (size_t)qi * rstride + h * 64;
        #pragma unroll
        for (int d = 0; d < 64; ++d)
            psi[ob + d] = f2bf(O[d] * rl + bf2f(rp[d]));
    } else {
        #pragma unroll
        for (int d = 0; d < 64; ++d)
            psi[ob + d] = f2bf(O[d] * rl);
    }
}

// ---------------- LayerNorm( gin + residual ) * g + b  -> f32 out
__global__ __launch_bounds__(256) void ln_ker(
    const float* __restrict__ gin, const float* __restrict__ resid,
    const float* __restrict__ g, const float* __restrict__ bta,
    float* __restrict__ out)
{
    const int row = blockIdx.x, tid = threadIdx.x;
    const size_t rb = (size_t)row * 768;
    float x[3], s = 0.f, s2 = 0.f;
    #pragma unroll
    for (int k2 = 0; k2 < 3; ++k2) {
        int c = k2 * 256 + tid;
        float v = gin[rb + c] + resid[rb + c];
        x[k2] = v; s += v; s2 += v * v;
    }
    #pragma unroll
    for (int off = 32; off > 0; off >>= 1) {
        s  += __shfl_down(s, off);
        s2 += __shfl_down(s2, off);
    }
    __shared__ float red[10];
    const int wv = tid >> 6;
    if ((tid & 63) == 0) { red[wv] = s; red[4 + wv] = s2; }
    __syncthreads();
    if (tid == 0) {
        float ts = red[0] + red[1] + red[2] + red[3];
        float t2 = red[4] + red[5] + red[6] + red[7];
        float mean = ts * (1.f / 768.f);
        float var = t2 * (1.f / 768.f) - mean * mean;
        red[8] = mean;
        red[9] = rsqrtf(fmaxf(var, 0.f) + 1e-6f);
    }
    __syncthreads();
    const float mean = red[8], rstd = red[9];
    #pragma unroll
    for (int k2 = 0; k2 < 3; ++k2) {
        int c = k2 * 256 + tid;
        out[rb + c] = (x[k2] - mean) * rstd * g[c] + bta[c];
    }
}

extern "C" void kernel_launch(void* const* d_in, const int* in_sizes, int n_in,
                              void* d_out, int out_size, void* d_ws, size_t ws_size,
                              hipStream_t stream) {
    const float* doc  = (const float*)d_in[0];
    const float* rel  = (const float*)d_in[1];
    const int*   mask = (const int*)d_in[2];
    const float* ln_dg = (const float*)d_in[10];
    const float* ln_db = (const float*)d_in[11];
    const float* ln_rg = (const float*)d_in[12];
    const float* ln_rb = (const float*)d_in[13];

    char* ws = (char*)d_ws;
    size_t off = 0;
    ushort* wtall = (ushort*)(ws + off); off += (size_t)7 * 768 * 768 * 2;
    ushort* wtqkv = wtall;
    ushort* wt34  = wtall + (size_t)3 * 768 * 768;
    ushort* wt5   = wtall + (size_t)5 * 768 * 768;
    ushort* wt6   = wtall + (size_t)6 * 768 * 768;
    ushort* doc_bf = (ushort*)(ws + off); off += (size_t)4096 * 768 * 2;
    ushort* rel_bf = (ushort*)(ws + off); off += (size_t)388 * 768 * 2;
    ushort* qkv_bf = (ushort*)(ws + off); off += (size_t)4096 * 2304 * 2;
    ushort* rkv_bf = (ushort*)(ws + off); off += (size_t)388 * 1536 * 2;
    float*  rks = (float*)(ws + off); off += (size_t)4 * 768 * 4;
    float*  rvs = (float*)(ws + off); off += (size_t)4 * 768 * 4;
    ushort* kf_bf = (ushort*)(ws + off); off += (size_t)4096 * 768 * 2;
    ushort* vf_bf = (ushort*)(ws + off); off += (size_t)4096 * 768 * 2;
    ushort* psi_i = (ushort*)(ws + off); off += (size_t)4096 * 768 * 2;
    ushort* psi_r = (ushort*)(ws + off); off += (size_t)388 * 768 * 2;
    float*  Mo = (float*)(ws + off);  off += (size_t)48 * 2 * 1024 * 4;
    float*  Lo = (float*)(ws + off);  off += (size_t)48 * 2 * 1024 * 4;
    ushort* Oo = (ushort*)(ws + off); off += (size_t)48 * 2 * 1024 * 64 * 2;
    float*  gdoc = (float*)(ws + off); off += (size_t)4096 * 768 * 4;
    float*  grel = (float*)(ws + off); off += (size_t)388 * 768 * 4;

    float* out_doc = (float*)d_out;
    float* out_rel = out_doc + (size_t)4096 * 768;

    // input converts + batched weight transpose
    const int n1 = 4096 * 768, n2 = 388 * 768;
    cvt_two<<<dim3((n1 + n2 + 255) / 256), 256, 0, stream>>>(doc, rel, doc_bf, rel_bf, n1, n2);
    transpose_all<<<dim3(24, 24, 7), dim3(32, 8), 0, stream>>>(
        (const float*)d_in[3], (const float*)d_in[4], (const float*)d_in[5],
        (const float*)d_in[6], (const float*)d_in[7], (const float*)d_in[8],
        (const float*)d_in[9], wtall);

    // fused projections (bf16 out)
    gemm_gl<true><<<dim3(32, 18), 256, 0, stream>>>(doc_bf, wtqkv, qkv_bf, 4096, 2304, 768);
    gemm64<true><<<dim3(7, 24),  256, 0, stream>>>(rel_bf, wt34, rkv_bf, 388, 1536, 768);

    // relation sums + fused K/V (bf16)
    relsum<<<dim3(4, 3), 256, 0, stream>>>(rkv_bf, rks, rvs);
    fusekv<<<dim3(4096, 3), 256, 0, stream>>>(qkv_bf, rks, rvs, kf_bf, vf_bf);

    // rel-doc attention on RAW k/v (qkv slices): 8 splits x 2 tiles
    attn_mfma<<<dim3(48, 2, 8), 256, 0, stream>>>(
        rkv_bf, 1536, (size_t)97 * 1536, 97,
        qkv_bf + 768, qkv_bf + 1536, 2304, (size_t)1024 * 2304,
        mask, Mo, Lo, Oo, 8, 2, 128);
    attn_merge<<<dim3(48, 2), 64, 0, stream>>>(
        Mo, Lo, Oo, rkv_bf + 768, (size_t)97 * 1536, 1536, psi_r, 8, 128, 97, 97);

    // doc-doc attention on fused K/V: 2 splits x 8 tiles
    attn_mfma<<<dim3(48, 16, 2), 256, 0, stream>>>(
        qkv_bf, 2304, (size_t)1024 * 2304, 1024,
        kf_bf, vf_bf, 768, (size_t)1024 * 768,
        mask, Mo, Lo, Oo, 2, 8, 1024);
    attn_merge<<<dim3(48, 16), 64, 0, stream>>>(
        Mo, Lo, Oo, (const ushort*)nullptr, 0, 0, psi_i, 2, 1024, 1024, 1024);

    // output projections on 64^2 grid (3 blocks/CU)
    gemm64<false><<<dim3(64, 12), 256, 0, stream>>>(psi_i, wt5, gdoc, 4096, 768, 768);
    gemm64<false><<<dim3(7, 12),  256, 0, stream>>>(psi_r, wt6, grel, 388, 768, 768);

    // layernorm + residual -> f32 outputs
    ln_ker<<<4096, 256, 0, stream>>>(gdoc, doc, ln_dg, ln_db, out_doc);
    ln_ker<<<388,  256, 0, stream>>>(grel, rel, ln_rg, ln_rb, out_rel);
}

// Round 11
// 184.071 us; speedup vs baseline: 1.1757x; 1.0720x over previous
//
#include <hip/hip_runtime.h>

typedef __attribute__((ext_vector_type(8))) short bt8;   // 8 bf16 (4 VGPR)
typedef __attribute__((ext_vector_type(4))) float f32x4; // 4 f32

__device__ __forceinline__ float bf2f(ushort u) {
    union { unsigned int i; float f; } v; v.i = ((unsigned int)u) << 16; return v.f;
}
__device__ __forceinline__ ushort f2bf(float f) {
    union { float f; unsigned int i; } v; v.f = f;
    unsigned int r = v.i + 0x7fffu + ((v.i >> 16) & 1u);
    return (ushort)(r >> 16);
}
__device__ __forceinline__ float fexp2(float x) { return __builtin_amdgcn_exp2f(x); }

#define GLOAD_LDS16(gp, lp) __builtin_amdgcn_global_load_lds( \
    (const __attribute__((address_space(1))) unsigned int*)(gp), \
    (__attribute__((address_space(3))) unsigned int*)(lp), 16, 0, 0)

// ---------------- fused f32 -> bf16 convert for doc + rel
__global__ __launch_bounds__(256) void cvt_two(
    const float* __restrict__ a, const float* __restrict__ b,
    ushort* __restrict__ oa, ushort* __restrict__ ob, int n1, int n2) {
    int i = blockIdx.x * 256 + threadIdx.x;
    if (i < n1) oa[i] = f2bf(a[i]);
    else if (i < n1 + n2) ob[i - n1] = f2bf(b[i - n1]);
}

// ---------------- batched weight transpose+convert: 7x W[768,768] f32 -> WT bf16 (out,in)
__global__ void transpose_all(const float* __restrict__ p0, const float* __restrict__ p1,
                              const float* __restrict__ p2, const float* __restrict__ p3,
                              const float* __restrict__ p4, const float* __restrict__ p5,
                              const float* __restrict__ p6, ushort* __restrict__ out) {
    __shared__ float t[32][33];
    const float* W;
    switch (blockIdx.z) {
        case 0: W = p0; break; case 1: W = p1; break; case 2: W = p2; break;
        case 3: W = p3; break; case 4: W = p4; break; case 5: W = p5; break;
        default: W = p6; break;
    }
    ushort* WT = out + (size_t)blockIdx.z * 768 * 768;
    int bx = blockIdx.x * 32, by = blockIdx.y * 32;
    int x = threadIdx.x, y0 = threadIdx.y;
    for (int y = y0; y < 32; y += 8)
        t[y][x] = W[(size_t)(by + y) * 768 + bx + x];
    __syncthreads();
    for (int y = y0; y < 32; y += 8)
        WT[(size_t)(bx + y) * 768 + by + x] = f2bf(t[x][y]);
}

// ---------------- m97-style MFMA GEMM 128x128: global_load_lds w16, linear LDS
template<bool BF16O>
__global__ __launch_bounds__(256) void gemm_gl(
    const ushort* __restrict__ A, const ushort* __restrict__ BT,
    void* __restrict__ Cv, int M, int N, int K)
{
    __shared__ ushort As[128 * 32];
    __shared__ ushort Bs[128 * 32];
    const int tid = threadIdx.x;
    const int wave = tid >> 6, lane = tid & 63;
    const int row0 = blockIdx.x * 128, col0 = blockIdx.y * 128;
    const int wm = (wave >> 1) * 64, wn = (wave & 1) * 64;
    const int lr = lane & 15, lk = (lane >> 4) * 8;
    const int srow = wave * 16 + (lane >> 2);
    const int scol = (lane & 3) * 8;

    f32x4 acc[4][4];
    #pragma unroll
    for (int mi = 0; mi < 4; ++mi)
        #pragma unroll
        for (int ni = 0; ni < 4; ++ni)
            acc[mi][ni] = (f32x4){0.f, 0.f, 0.f, 0.f};

    int ar0 = row0 + srow;       if (ar0 >= M) ar0 = M - 1;
    int ar1 = row0 + 64 + srow;  if (ar1 >= M) ar1 = M - 1;
    const int bc0 = col0 + srow, bc1 = col0 + 64 + srow;

    for (int kt = 0; kt < K; kt += 32) {
        __syncthreads();
        GLOAD_LDS16(A + (size_t)ar0 * K + kt + scol, As + wave * 512);
        GLOAD_LDS16(A + (size_t)ar1 * K + kt + scol, As + 2048 + wave * 512);
        GLOAD_LDS16(BT + (size_t)bc0 * K + kt + scol, Bs + wave * 512);
        GLOAD_LDS16(BT + (size_t)bc1 * K + kt + scol, Bs + 2048 + wave * 512);
        __syncthreads();
        bt8 af[4], bf[4];
        #pragma unroll
        for (int mi = 0; mi < 4; ++mi)
            af[mi] = *(const bt8*)&As[(wm + mi * 16 + lr) * 32 + lk];
        #pragma unroll
        for (int ni = 0; ni < 4; ++ni)
            bf[ni] = *(const bt8*)&Bs[(wn + ni * 16 + lr) * 32 + lk];
        #pragma unroll
        for (int mi = 0; mi < 4; ++mi)
            #pragma unroll
            for (int ni = 0; ni < 4; ++ni)
                acc[mi][ni] = __builtin_amdgcn_mfma_f32_16x16x32_bf16(
                    af[mi], bf[ni], acc[mi][ni], 0, 0, 0);
    }

    #pragma unroll
    for (int mi = 0; mi < 4; ++mi) {
        int orow0 = row0 + wm + mi * 16 + (lane >> 4) * 4;
        #pragma unroll
        for (int ni = 0; ni < 4; ++ni) {
            int ocol = col0 + wn + ni * 16 + lr;
            if (ocol >= N) continue;
            #pragma unroll
            for (int r2 = 0; r2 < 4; ++r2) {
                int orow = orow0 + r2;
                if (orow < M) {
                    if (BF16O)
                        ((ushort*)Cv)[(size_t)orow * N + ocol] = f2bf(acc[mi][ni][r2]);
                    else
                        ((float*)Cv)[(size_t)orow * N + ocol] = acc[mi][ni][r2];
                }
            }
        }
    }
}

// ---------------- 64x64 MFMA GEMM for small/narrow shapes (better grid fill)
template<bool BF16O>
__global__ __launch_bounds__(256) void gemm64(
    const ushort* __restrict__ A, const ushort* __restrict__ BT,
    void* __restrict__ Cv, int M, int N, int K)
{
    __shared__ ushort As[64 * 32];
    __shared__ ushort Bs[64 * 32];
    const int tid = threadIdx.x;
    const int wave = tid >> 6, lane = tid & 63;
    const int row0 = blockIdx.x * 64, col0 = blockIdx.y * 64;
    const int wm = (wave >> 1) * 32, wn = (wave & 1) * 32;
    const int lr = lane & 15, lk = (lane >> 4) * 8;
    const int srow = tid >> 2;          // 0..63
    const int scol = (tid & 3) * 8;

    f32x4 acc[2][2];
    #pragma unroll
    for (int mi = 0; mi < 2; ++mi)
        #pragma unroll
        for (int ni = 0; ni < 2; ++ni)
            acc[mi][ni] = (f32x4){0.f, 0.f, 0.f, 0.f};

    int ar = row0 + srow; if (ar >= M) ar = M - 1;
    const int bc = col0 + srow;

    for (int kt = 0; kt < K; kt += 32) {
        __syncthreads();
        GLOAD_LDS16(A + (size_t)ar * K + kt + scol, As + wave * 512);
        GLOAD_LDS16(BT + (size_t)bc * K + kt + scol, Bs + wave * 512);
        __syncthreads();
        bt8 af[2], bf[2];
        #pragma unroll
        for (int mi = 0; mi < 2; ++mi)
            af[mi] = *(const bt8*)&As[(wm + mi * 16 + lr) * 32 + lk];
        #pragma unroll
        for (int ni = 0; ni < 2; ++ni)
            bf[ni] = *(const bt8*)&Bs[(wn + ni * 16 + lr) * 32 + lk];
        #pragma unroll
        for (int mi = 0; mi < 2; ++mi)
            #pragma unroll
            for (int ni = 0; ni < 2; ++ni)
                acc[mi][ni] = __builtin_amdgcn_mfma_f32_16x16x32_bf16(
                    af[mi], bf[ni], acc[mi][ni], 0, 0, 0);
    }

    #pragma unroll
    for (int mi = 0; mi < 2; ++mi) {
        int orow0 = row0 + wm + mi * 16 + (lane >> 4) * 4;
        #pragma unroll
        for (int ni = 0; ni < 2; ++ni) {
            int ocol = col0 + wn + ni * 16 + lr;
            if (ocol >= N) continue;
            #pragma unroll
            for (int r2 = 0; r2 < 4; ++r2) {
                int orow = orow0 + r2;
                if (orow < M) {
                    if (BF16O)
                        ((ushort*)Cv)[(size_t)orow * N + ocol] = f2bf(acc[mi][ni][r2]);
                    else
                        ((float*)Cv)[(size_t)orow * N + ocol] = acc[mi][ni][r2];
                }
            }
        }
    }
}

// ---------------- per-(b) column sums of rel K/V from fused rkv (bf16, stride 1536)
__global__ void relsum(const ushort* __restrict__ rkv,
                       float* __restrict__ rks, float* __restrict__ rvs) {
    int b = blockIdx.x;
    int c = blockIdx.y * 256 + threadIdx.x;
    float s1 = 0.f, s2 = 0.f;
    for (int r = 0; r < 97; ++r) {
        const ushort* row = rkv + (size_t)(b * 97 + r) * 1536;
        s1 += bf2f(row[c]);
        s2 += bf2f(row[768 + c]);
    }
    rks[b * 768 + c] = s1;
    rvs[b * 768 + c] = s2;
}

// ---------------- fused_k/fused_v (bf16)
__global__ __launch_bounds__(256) void fusekv(
    const ushort* __restrict__ qkv, const float* __restrict__ rks,
    const float* __restrict__ rvs, ushort* __restrict__ kf, ushort* __restrict__ vf)
{
    int row = blockIdx.x;
    int c = blockIdx.y * 256 + threadIdx.x;
    int b = row >> 10;
    size_t qi = (size_t)row * 2304;
    size_t oi = (size_t)row * 768 + c;
    kf[oi] = f2bf(bf2f(qkv[qi + 768 + c]) + rks[b * 768 + c]);
    vf[oi] = f2bf(bf2f(qkv[qi + 1536 + c]) + rvs[b * 768 + c]);
}

// ---------------- MFMA flash attention (split-K optional), exp2 softmax, defer-max
// Block: 256 thr = 4 waves, each wave owns 16 q-rows (block = 64 q-rows).
// If psiD != nullptr (requires nspl==1): normalize + write psi directly.
#define SC2 0.18033688011112042f   // 0.125 * log2(e)
#define THR2 10.0f

__global__ __launch_bounds__(256) void attn_mfma(
    const ushort* __restrict__ Qp, int qstride, size_t qbstride, int qmax,
    const ushort* __restrict__ Kp, const ushort* __restrict__ Vp,
    int kvstride, size_t kvbstride,
    const int* __restrict__ mask,
    float* __restrict__ Mo, float* __restrict__ Lo, ushort* __restrict__ Oo,
    int nspl, int ntiles, int qrows,
    ushort* __restrict__ psiD, int out_rows)
{
    __shared__ ushort Ks[64 * 64];      // [key][k], hw ^= (key&7)<<3
    __shared__ ushort Vt[64 * 64];      // [d][key], hw ^= (d&7)<<3
    __shared__ ushort Ps[4][16 * 64];   // per-wave [qrow][key], hw ^= (row&7)<<3
    __shared__ float  madd[64];

    const int tid = threadIdx.x;
    const int wv = tid >> 6, lane = tid & 63;
    const int lr = lane & 15, lk = (lane >> 4) * 8, rg = lane >> 4;
    const int bh = blockIdx.x, b = bh / 12, h = bh % 12;
    const int qb = blockIdx.y, spl = blockIdx.z;
    const int q0 = qb * 64 + wv * 16;

    const size_t kvbase = (size_t)b * kvbstride + h * 64;
    const size_t qbase  = (size_t)b * qbstride + h * 64;

    // Q fragments (bf16 direct)
    bt8 qf[2];
    {
        const int qi = q0 + lr;
        if (qi < qmax) {
            const ushort* qp = Qp + qbase + (size_t)qi * qstride + lk;
            qf[0] = *(const bt8*)qp;
            qf[1] = *(const bt8*)(qp + 32);
        } else {
            #pragma unroll
            for (int j = 0; j < 8; ++j) { qf[0][j] = 0; qf[1][j] = 0; }
        }
    }

    f32x4 acc[4];
    #pragma unroll
    for (int dg = 0; dg < 4; ++dg) acc[dg] = (f32x4){0.f, 0.f, 0.f, 0.f};
    float m_r[4], l_r[4];
    #pragma unroll
    for (int r = 0; r < 4; ++r) { m_r[r] = -3.0e38f; l_r[r] = 0.f; }

    const int key = tid >> 2, c0 = (tid & 3) * 16;  // K staging
    const int vd = tid & 63, vw = tid >> 6;         // V staging (column gather)
    const int swk = (key & 7) << 3;
    const int swv = (vd & 7) << 3;
    const int swl = (lr & 7) << 3;

    for (int t = 0; t < ntiles; ++t) {
        const int k0 = (spl * ntiles + t) * 64;
        __syncthreads();
        {
            const ushort* src = Kp + kvbase + (size_t)(k0 + key) * kvstride + c0;
            int4 a = *(const int4*)src;
            int4 bq = *(const int4*)(src + 8);
            *(int4*)&Ks[key * 64 + (c0 ^ swk)] = a;
            *(int4*)&Ks[key * 64 + ((c0 + 8) ^ swk)] = bq;
        }
        {
            const ushort* vsrc = Vp + kvbase + (size_t)(k0 + vw * 16) * kvstride + vd;
            ushort tv[16];
            #pragma unroll
            for (int j = 0; j < 16; ++j) tv[j] = vsrc[(size_t)j * kvstride];
            const int cc = vw * 16;
            *(int4*)&Vt[vd * 64 + (cc ^ swv)] = *(int4*)tv;
            *(int4*)&Vt[vd * 64 + ((cc + 8) ^ swv)] = *(int4*)(tv + 8);
        }
        if (tid < 64)
            madd[tid] = (mask[b * 1024 + k0 + tid] == 0) ? -1e30f : 0.f;
        __syncthreads();

        // S = Q K^T (swizzled Ks reads)
        f32x4 sf[4];
        #pragma unroll
        for (int kg = 0; kg < 4; ++kg) {
            f32x4 s4 = (f32x4){0.f, 0.f, 0.f, 0.f};
            #pragma unroll
            for (int kk = 0; kk < 2; ++kk) {
                bt8 kf2 = *(const bt8*)&Ks[(kg * 16 + lr) * 64 + ((kk * 32 + lk) ^ swl)];
                s4 = __builtin_amdgcn_mfma_f32_16x16x32_bf16(qf[kk], kf2, s4, 0, 0, 0);
            }
            sf[kg] = s4;
        }

        // online softmax in exp2 domain (native v_exp), defer-max
        #pragma unroll
        for (int r = 0; r < 4; ++r) {
            float sv0 = sf[0][r] * SC2 + madd[lr];
            float sv1 = sf[1][r] * SC2 + madd[16 + lr];
            float sv2 = sf[2][r] * SC2 + madd[32 + lr];
            float sv3 = sf[3][r] * SC2 + madd[48 + lr];
            float mx = fmaxf(fmaxf(sv0, sv1), fmaxf(sv2, sv3));
            mx = fmaxf(mx, __shfl_xor(mx, 1));
            mx = fmaxf(mx, __shfl_xor(mx, 2));
            mx = fmaxf(mx, __shfl_xor(mx, 4));
            mx = fmaxf(mx, __shfl_xor(mx, 8));
            float m_old = m_r[r];
            if (mx > m_old + THR2) {
                float corr = fexp2(m_old - mx);
                m_r[r] = mx;
                l_r[r] *= corr;
                #pragma unroll
                for (int dg = 0; dg < 4; ++dg) acc[dg][r] *= corr;
            }
            const float mn = m_r[r];
            float p0 = fexp2(sv0 - mn), p1 = fexp2(sv1 - mn);
            float p2 = fexp2(sv2 - mn), p3 = fexp2(sv3 - mn);
            float ps = (p0 + p1) + (p2 + p3);
            ps += __shfl_xor(ps, 1);
            ps += __shfl_xor(ps, 2);
            ps += __shfl_xor(ps, 4);
            ps += __shfl_xor(ps, 8);
            l_r[r] += ps;
            const int rowq = rg * 4 + r;
            const int swp = (rowq & 7) << 3;
            Ps[wv][rowq * 64 + ((0 * 16 + lr) ^ swp)] = f2bf(p0);
            Ps[wv][rowq * 64 + ((1 * 16 + lr) ^ swp)] = f2bf(p1);
            Ps[wv][rowq * 64 + ((2 * 16 + lr) ^ swp)] = f2bf(p2);
            Ps[wv][rowq * 64 + ((3 * 16 + lr) ^ swp)] = f2bf(p3);
        }

        // PV (swizzled Ps / Vt reads)
        #pragma unroll
        for (int kk = 0; kk < 2; ++kk) {
            bt8 pa = *(const bt8*)&Ps[wv][lr * 64 + ((kk * 32 + lk) ^ swl)];
            #pragma unroll
            for (int dg = 0; dg < 4; ++dg) {
                bt8 vf2 = *(const bt8*)&Vt[(dg * 16 + lr) * 64 + ((kk * 32 + lk) ^ swl)];
                acc[dg] = __builtin_amdgcn_mfma_f32_16x16x32_bf16(pa, vf2, acc[dg], 0, 0, 0);
            }
        }
    }

    if (psiD) {
        // direct normalized output (nspl==1): psi[b, qi, h*64 + dg*16+lr]
        #pragma unroll
        for (int r = 0; r < 4; ++r) {
            int qi = q0 + rg * 4 + r;
            if (qi >= qmax) continue;
            float rl = 1.f / l_r[r];
            size_t ob = ((size_t)b * out_rows + qi) * 768 + h * 64;
            #pragma unroll
            for (int dg = 0; dg < 4; ++dg)
                psiD[ob + dg * 16 + lr] = f2bf(acc[dg][r] * rl);
        }
    } else {
        if (lr == 0) {
            #pragma unroll
            for (int r = 0; r < 4; ++r) {
                int qi = q0 + rg * 4 + r;
                int prow = (bh * nspl + spl) * qrows + qi;
                Mo[prow] = m_r[r];
                Lo[prow] = l_r[r];
            }
        }
        #pragma unroll
        for (int r = 0; r < 4; ++r) {
            int qi = q0 + rg * 4 + r;
            size_t orow = ((size_t)(bh * nspl + spl) * qrows + qi) * 64;
            #pragma unroll
            for (int dg = 0; dg < 4; ++dg)
                Oo[orow + dg * 16 + lr] = f2bf(acc[dg][r]);
        }
    }
}

// ---------------- merge split partials (exp2 domain) -> psi (bf16)
__global__ __launch_bounds__(64) void attn_merge(
    const float* __restrict__ Mo, const float* __restrict__ Lo, const ushort* __restrict__ Oo,
    const ushort* __restrict__ resid, size_t rbstride, int rstride,
    ushort* __restrict__ psi,
    int nspl, int qrows, int qmax, int out_rows)
{
    const int tid = threadIdx.x, bh = blockIdx.x, qb = blockIdx.y;
    const int b = bh / 12, h = bh % 12;
    const int qi = qb * 64 + tid;
    if (qi >= qmax) return;
    const int pb = bh * nspl;

    float M = -3.0e38f;
    for (int s = 0; s < nspl; ++s)
        M = fmaxf(M, Mo[(pb + s) * qrows + qi]);
    float L = 0.f, O[64];
    #pragma unroll
    for (int d = 0; d < 64; ++d) O[d] = 0.f;
    for (int s = 0; s < nspl; ++s) {
        int pr = (pb + s) * qrows + qi;
        float f = fexp2(Mo[pr] - M);
        L += Lo[pr] * f;
        const uint* op = (const uint*)(Oo + (size_t)pr * 64);
        #pragma unroll
        for (int d2 = 0; d2 < 32; ++d2) {
            uint u = op[d2];
            O[2*d2]   += f * bf2f((ushort)(u & 0xffffu));
            O[2*d2+1] += f * bf2f((ushort)(u >> 16));
        }
    }
    const float rl = 1.f / L;
    const size_t ob = ((size_t)b * out_rows + qi) * 768 + h * 64;
    if (resid) {
        const ushort* rp = resid + (size_t)b * rbstride + (size_t)qi * rstride + h * 64;
        #pragma unroll
        for (int d = 0; d < 64; ++d)
            psi[ob + d] = f2bf(O[d] * rl + bf2f(rp[d]));
    } else {
        #pragma unroll
        for (int d = 0; d < 64; ++d)
            psi[ob + d] = f2bf(O[d] * rl);
    }
}

// ---------------- LayerNorm( gin + residual ) * g + b  -> f32 out
__global__ __launch_bounds__(256) void ln_ker(
    const float* __restrict__ gin, const float* __restrict__ resid,
    const float* __restrict__ g, const float* __restrict__ bta,
    float* __restrict__ out)
{
    const int row = blockIdx.x, tid = threadIdx.x;
    const size_t rb = (size_t)row * 768;
    float x[3], s = 0.f, s2 = 0.f;
    #pragma unroll
    for (int k2 = 0; k2 < 3; ++k2) {
        int c = k2 * 256 + tid;
        float v = gin[rb + c] + resid[rb + c];
        x[k2] = v; s += v; s2 += v * v;
    }
    #pragma unroll
    for (int off = 32; off > 0; off >>= 1) {
        s  += __shfl_down(s, off);
        s2 += __shfl_down(s2, off);
    }
    __shared__ float red[10];
    const int wv = tid >> 6;
    if ((tid & 63) == 0) { red[wv] = s; red[4 + wv] = s2; }
    __syncthreads();
    if (tid == 0) {
        float ts = red[0] + red[1] + red[2] + red[3];
        float t2 = red[4] + red[5] + red[6] + red[7];
        float mean = ts * (1.f / 768.f);
        float var = t2 * (1.f / 768.f) - mean * mean;
        red[8] = mean;
        red[9] = rsqrtf(fmaxf(var, 0.f) + 1e-6f);
    }
    __syncthreads();
    const float mean = red[8], rstd = red[9];
    #pragma unroll
    for (int k2 = 0; k2 < 3; ++k2) {
        int c = k2 * 256 + tid;
        out[rb + c] = (x[k2] - mean) * rstd * g[c] + bta[c];
    }
}

extern "C" void kernel_launch(void* const* d_in, const int* in_sizes, int n_in,
                              void* d_out, int out_size, void* d_ws, size_t ws_size,
                              hipStream_t stream) {
    const float* doc  = (const float*)d_in[0];
    const float* rel  = (const float*)d_in[1];
    const int*   mask = (const int*)d_in[2];
    const float* ln_dg = (const float*)d_in[10];
    const float* ln_db = (const float*)d_in[11];
    const float* ln_rg = (const float*)d_in[12];
    const float* ln_rb = (const float*)d_in[13];

    char* ws = (char*)d_ws;
    size_t off = 0;
    ushort* wtall = (ushort*)(ws + off); off += (size_t)7 * 768 * 768 * 2;
    ushort* wtqkv = wtall;
    ushort* wt34  = wtall + (size_t)3 * 768 * 768;
    ushort* wt5   = wtall + (size_t)5 * 768 * 768;
    ushort* wt6   = wtall + (size_t)6 * 768 * 768;
    ushort* doc_bf = (ushort*)(ws + off); off += (size_t)4096 * 768 * 2;
    ushort* rel_bf = (ushort*)(ws + off); off += (size_t)388 * 768 * 2;
    ushort* qkv_bf = (ushort*)(ws + off); off += (size_t)4096 * 2304 * 2;
    ushort* rkv_bf = (ushort*)(ws + off); off += (size_t)388 * 1536 * 2;
    float*  rks = (float*)(ws + off); off += (size_t)4 * 768 * 4;
    float*  rvs = (float*)(ws + off); off += (size_t)4 * 768 * 4;
    ushort* kf_bf = (ushort*)(ws + off); off += (size_t)4096 * 768 * 2;
    ushort* vf_bf = (ushort*)(ws + off); off += (size_t)4096 * 768 * 2;
    ushort* psi_i = (ushort*)(ws + off); off += (size_t)4096 * 768 * 2;
    ushort* psi_r = (ushort*)(ws + off); off += (size_t)388 * 768 * 2;
    float*  Mo = (float*)(ws + off);  off += (size_t)48 * 8 * 128 * 4;
    float*  Lo = (float*)(ws + off);  off += (size_t)48 * 8 * 128 * 4;
    ushort* Oo = (ushort*)(ws + off); off += (size_t)48 * 8 * 128 * 64 * 2;
    float*  gdoc = (float*)(ws + off); off += (size_t)4096 * 768 * 4;
    float*  grel = (float*)(ws + off); off += (size_t)388 * 768 * 4;

    float* out_doc = (float*)d_out;
    float* out_rel = out_doc + (size_t)4096 * 768;

    // input converts + batched weight transpose
    const int n1 = 4096 * 768, n2 = 388 * 768;
    cvt_two<<<dim3((n1 + n2 + 255) / 256), 256, 0, stream>>>(doc, rel, doc_bf, rel_bf, n1, n2);
    transpose_all<<<dim3(24, 24, 7), dim3(32, 8), 0, stream>>>(
        (const float*)d_in[3], (const float*)d_in[4], (const float*)d_in[5],
        (const float*)d_in[6], (const float*)d_in[7], (const float*)d_in[8],
        (const float*)d_in[9], wtall);

    // fused projections (bf16 out)
    gemm_gl<true><<<dim3(32, 18), 256, 0, stream>>>(doc_bf, wtqkv, qkv_bf, 4096, 2304, 768);
    gemm64<true><<<dim3(7, 24),  256, 0, stream>>>(rel_bf, wt34, rkv_bf, 388, 1536, 768);

    // relation sums + fused K/V (bf16)
    relsum<<<dim3(4, 3), 256, 0, stream>>>(rkv_bf, rks, rvs);
    fusekv<<<dim3(4096, 3), 256, 0, stream>>>(qkv_bf, rks, rvs, kf_bf, vf_bf);

    // rel-doc attention on RAW k/v (qkv slices): 8 splits x 2 tiles (partials + merge)
    attn_mfma<<<dim3(48, 2, 8), 256, 0, stream>>>(
        rkv_bf, 1536, (size_t)97 * 1536, 97,
        qkv_bf + 768, qkv_bf + 1536, 2304, (size_t)1024 * 2304,
        mask, Mo, Lo, Oo, 8, 2, 128, (ushort*)nullptr, 0);
    attn_merge<<<dim3(48, 2), 64, 0, stream>>>(
        Mo, Lo, Oo, rkv_bf + 768, (size_t)97 * 1536, 1536, psi_r, 8, 128, 97, 97);

    // doc-doc attention on fused K/V: no split, direct psi write
    attn_mfma<<<dim3(48, 16, 1), 256, 0, stream>>>(
        qkv_bf, 2304, (size_t)1024 * 2304, 1024,
        kf_bf, vf_bf, 768, (size_t)1024 * 768,
        mask, Mo, Lo, Oo, 1, 16, 1024, psi_i, 1024);

    // output projections on 64^2 grid (3 blocks/CU)
    gemm64<false><<<dim3(64, 12), 256, 0, stream>>>(psi_i, wt5, gdoc, 4096, 768, 768);
    gemm64<false><<<dim3(7, 12),  256, 0, stream>>>(psi_r, wt6, grel, 388, 768, 768);

    // layernorm + residual -> f32 outputs
    ln_ker<<<4096, 256, 0, stream>>>(gdoc, doc, ln_dg, ln_db, out_doc);
    ln_ker<<<388,  256, 0, stream>>>(grel, rel, ln_rg, ln_rb, out_rel);
}